// Round 2
// baseline (291.923 us; speedup 1.0000x reference)
//
#include <hip/hip_runtime.h>
#include <hip/hip_bf16.h>

#define N2    16384
#define NHALF 8192
#define KDIM  128
#define BROW  128      // rows per block
#define BCOL  256      // B-tile cols per iteration
#define NQUARTER 4096  // cols per block (grid = 128 row-tiles x 4 col-quarters)

using bf16x8 = __attribute__((ext_vector_type(8))) short;
using f32x4  = __attribute__((ext_vector_type(4))) float;

#if __has_builtin(__builtin_amdgcn_exp2f)
#define EXP2F(x) __builtin_amdgcn_exp2f(x)
#else
#define EXP2F(x) exp2f(x)
#endif
#if __has_builtin(__builtin_amdgcn_logf)
#define LOG2F(x) __builtin_amdgcn_logf(x)
#else
#define LOG2F(x) log2f(x)
#endif

__device__ __forceinline__ unsigned short f2bf(float f) {
  unsigned u = __float_as_uint(f);
  u += 0x7fffu + ((u >> 16) & 1u);   // RNE
  return (unsigned short)(u >> 16);
}

// ---- K1: f32 -> bf16 conversion (z -> zb) + zero S and out (fused init) ----
__global__ void k_convert(const float* __restrict__ z, unsigned short* __restrict__ zb,
                          float* __restrict__ S, float* __restrict__ out) {
  int i = blockIdx.x * blockDim.x + threadIdx.x;  // over N2*KDIM/4
  if (i < N2) S[i] = 0.f;
  if (i == 0) out[0] = 0.f;
  float4 v = reinterpret_cast<const float4*>(z)[i];
  ushort4 o;
  o.x = f2bf(v.x); o.y = f2bf(v.y); o.z = f2bf(v.z); o.w = f2bf(v.w);
  reinterpret_cast<ushort4*>(zb)[i] = o;
}

// ---- K2: fused sim = 2*z@z^T -> exp -> row sums (diagonal masked) ----
// grid = 512 blocks: (row-tile bt = bx>>2) x (column quarter = bx&3)
// block = 512 threads = 8 waves: 2 row-groups x 4 col-strips, 64x64 per wave
// LDS: 256 rows x 128 bf16, XOR-swizzled at 16B-granule granularity:
//   granule k8 of row r stored at physical granule (k8 ^ (r & 15)).
// Bank check (reads): addr_dw = r*64 + pg*4 + j, pg = (4s+q) ^ c15 -> across the
// 64 lanes each of the 32 banks receives exactly 8 dword accesses (uniform =
// conflict-free minimum). Writes: k8 = t&15 spans all 16 granules per row ->
// same uniform spread. LDS = exactly 64 KB -> 2 blocks/CU fit (128 <= 160 KB).
__global__ __launch_bounds__(512, 4) void k_main(const unsigned short* __restrict__ zb,
                                                 float* __restrict__ S) {
  __shared__ __align__(16) unsigned short Bs[BCOL * KDIM];
  const int t    = threadIdx.x;
  const int w    = t >> 6;
  const int l    = t & 63;
  const int q    = l >> 4;    // quad within wave
  const int c15  = l & 15;
  const int bt      = blockIdx.x >> 2;
  const int quarter = blockIdx.x & 3;
  const int mg   = w >> 2;    // which 64-row group
  const int ns   = w & 3;     // which 64-col strip
  const int rbase = bt * BROW + mg * 64;

  // A fragments for this wave's 64 rows, full K=128, held in registers all kernel.
  // a-frag layout (16x16x32): lane holds A[m=lane&15][k=(lane>>4)*8 + j]
  bf16x8 afr[4][4];
#pragma unroll
  for (int m = 0; m < 4; ++m) {
    const unsigned short* ap = zb + (size_t)(rbase + m * 16 + c15) * KDIM + q * 8;
#pragma unroll
    for (int s = 0; s < 4; ++s)
      afr[m][s] = *reinterpret_cast<const bf16x8*>(ap + s * 32);
  }

  float rowsum[4][4];
#pragma unroll
  for (int m = 0; m < 4; ++m)
#pragma unroll
    for (int r = 0; r < 4; ++r) rowsum[m][r] = 0.f;

  const float kExpScale = 2.8853900817779268f;  // 2 * log2(e): exp(2*dot) = exp2(dot*this)

  for (int it = 0; it < NQUARTER / BCOL; ++it) {
    const int C0 = quarter * NQUARTER + it * BCOL;
    __syncthreads();
    // stage B tile (rows C0..C0+255 of zb) -> swizzled LDS; coalesced 16B granules
    {
      const int4* src = reinterpret_cast<const int4*>(zb + (size_t)C0 * KDIM);
#pragma unroll
      for (int p = 0; p < 8; ++p) {
        int g   = p * 512 + t;   // granule id, 16 B each; 16 granules per row
        int row = g >> 4;
        int k8  = g & 15;
        int4 v  = src[g];
        int pg  = k8 ^ (row & 15);
        *reinterpret_cast<int4*>(&Bs[row * KDIM + pg * 8]) = v;
      }
    }
    __syncthreads();

    f32x4 acc[4][4];
#pragma unroll
    for (int m = 0; m < 4; ++m)
#pragma unroll
      for (int n = 0; n < 4; ++n) acc[m][n] = (f32x4){0.f, 0.f, 0.f, 0.f};

#pragma unroll
    for (int s = 0; s < 4; ++s) {
      bf16x8 bfr[4];
#pragma unroll
      for (int n = 0; n < 4; ++n) {
        int rloc = ns * 64 + n * 16 + c15;
        int pg   = (s * 4 + q) ^ (rloc & 15);
        bfr[n] = *reinterpret_cast<const bf16x8*>(&Bs[rloc * KDIM + pg * 8]);
      }
#pragma unroll
      for (int m = 0; m < 4; ++m)
#pragma unroll
        for (int n = 0; n < 4; ++n)
          acc[m][n] = __builtin_amdgcn_mfma_f32_16x16x32_bf16(afr[m][s], bfr[n], acc[m][n], 0, 0, 0);
    }

    // epilogue: exp and accumulate row sums; mask diagonal when this wave's
    // 64x64 strip sits on it (wave-uniform condition)
    const bool diagTile = (C0 + ns * 64) == rbase;
    if (diagTile) {
#pragma unroll
      for (int m = 0; m < 4; ++m)
#pragma unroll
        for (int n = 0; n < 4; ++n)
#pragma unroll
          for (int r = 0; r < 4; ++r) {
            float e = EXP2F(acc[m][n][r] * kExpScale);
            if ((m == n) && (c15 == q * 4 + r)) e = 0.f;  // sim[i][i] masked
            rowsum[m][r] += e;
          }
    } else {
#pragma unroll
      for (int m = 0; m < 4; ++m)
#pragma unroll
        for (int n = 0; n < 4; ++n)
#pragma unroll
          for (int r = 0; r < 4; ++r) {
            rowsum[m][r] += EXP2F(acc[m][n][r] * kExpScale);
          }
    }
  }

  // reduce across the 16 column-lanes (masks 1,2,4,8 stay within a quad),
  // then one atomicAdd per row-partial
#pragma unroll
  for (int m = 0; m < 4; ++m)
#pragma unroll
    for (int r = 0; r < 4; ++r) {
      float v = rowsum[m][r];
      v += __shfl_xor(v, 1);
      v += __shfl_xor(v, 2);
      v += __shfl_xor(v, 4);
      v += __shfl_xor(v, 8);
      if (c15 == 0) atomicAdd(&S[rbase + m * 16 + q * 4 + r], v);
    }
}

// ---- K3: loss_i = log(S_i) - 2*z_i.z_pair(i); mean into out ----
__global__ void k_final(const float* __restrict__ z, const float* __restrict__ S,
                        float* __restrict__ out) {
  __shared__ float red[256];
  int t = threadIdx.x;
  int i = blockIdx.x * 256 + t;
  int j = i ^ NHALF;  // positive pair index
  const float4* zi = reinterpret_cast<const float4*>(z + (size_t)i * KDIM);
  const float4* zj = reinterpret_cast<const float4*>(z + (size_t)j * KDIM);
  float dot = 0.f;
#pragma unroll
  for (int k = 0; k < KDIM / 4; ++k) {
    float4 a = zi[k], b = zj[k];
    dot += a.x * b.x + a.y * b.y + a.z * b.z + a.w * b.w;
  }
  float loss = LOG2F(S[i]) * 0.69314718055994531f - 2.f * dot;
  red[t] = loss;
  __syncthreads();
  for (int o = 128; o > 0; o >>= 1) {
    if (t < o) red[t] += red[t + o];
    __syncthreads();
  }
  if (t == 0) atomicAdd(out, red[0] * (1.f / N2));
}

extern "C" void kernel_launch(void* const* d_in, const int* in_sizes, int n_in,
                              void* d_out, int out_size, void* d_ws, size_t ws_size,
                              hipStream_t stream) {
  const float* z = (const float*)d_in[0];
  float* out = (float*)d_out;
  unsigned short* zb = (unsigned short*)d_ws;                       // 4 MB bf16 copy of z
  float* S = (float*)((char*)d_ws + (size_t)N2 * KDIM * 2);         // 64 KB row sums

  k_convert<<<(N2 * KDIM / 4) / 256, 256, 0, stream>>>(z, zb, S, out);
  k_main<<<512, 512, 0, stream>>>(zb, S);
  k_final<<<N2 / 256, 256, 0, stream>>>(z, S, out);
}

// Round 3
// 140.384 us; speedup vs baseline: 2.0795x; 2.0795x over previous
//
#include <hip/hip_runtime.h>
#include <hip/hip_bf16.h>

#define N2    16384
#define NHALF 8192
#define KDIM  128
#define BROW  128      // rows per block
#define BCOL  256      // B-tile cols per iteration
#define NQUARTER 4096  // cols per block (grid = 128 row-tiles x 4 col-quarters)
#define NITER (NQUARTER / BCOL)   // 16

using bf16x8 = __attribute__((ext_vector_type(8))) short;
using f32x4  = __attribute__((ext_vector_type(4))) float;

#if __has_builtin(__builtin_amdgcn_exp2f)
#define EXP2F(x) __builtin_amdgcn_exp2f(x)
#else
#define EXP2F(x) exp2f(x)
#endif
#if __has_builtin(__builtin_amdgcn_logf)
#define LOG2F(x) __builtin_amdgcn_logf(x)
#else
#define LOG2F(x) log2f(x)
#endif

// exp(2*dot) == exp2(dot * 2*log2(e)); we fold sqrt(2*log2(e)) into each z
// at convert time so the MFMA result is already in exp2 domain.
#define PRESCALE 1.6986436005760381f   // sqrt(2*log2(e))

typedef const __attribute__((address_space(1))) void* gas_ptr;
typedef __attribute__((address_space(3))) void* las_ptr;

__device__ __forceinline__ unsigned short f2bf(float f) {
  unsigned u = __float_as_uint(f);
  u += 0x7fffu + ((u >> 16) & 1u);   // RNE
  return (unsigned short)(u >> 16);
}

// ---- K1: f32 -> bf16 conversion with PRESCALE (z -> zb) + zero S and out ----
__global__ void k_convert(const float* __restrict__ z, unsigned short* __restrict__ zb,
                          float* __restrict__ S, float* __restrict__ out) {
  int i = blockIdx.x * blockDim.x + threadIdx.x;  // over N2*KDIM/4
  if (i < N2) S[i] = 0.f;
  if (i == 0) out[0] = 0.f;
  float4 v = reinterpret_cast<const float4*>(z)[i];
  ushort4 o;
  o.x = f2bf(v.x * PRESCALE); o.y = f2bf(v.y * PRESCALE);
  o.z = f2bf(v.z * PRESCALE); o.w = f2bf(v.w * PRESCALE);
  reinterpret_cast<ushort4*>(zb)[i] = o;
}

// ---- K2: fused sim -> exp -> row sums (diagonal masked) ----
// grid = 512: (row-tile bt = bx>>2) x (col quarter = bx&3)
// block = 512 = 8 waves: 2 row-groups x 4 col-strips, 64x64 per wave.
// A (64 rows x K=128 per wave) lives in registers for the whole kernel.
// B tiles: double-buffered LDS (2 x 64 KB), filled by async global_load_lds
// DMA. The XOR granule swizzle (data granule (row,k8) stored at physical
// granule (row, k8^(row&15))) is applied on the *source* addresses, since the
// DMA's LDS destination is always wave-uniform-base + lane*16 (lane-linear).
// Read-side bank math (verified R2: SQ_LDS_BANK_CONFLICT == 0).
// NOTE: __launch_bounds__ min-waves stays at 2 — R2 showed forcing 4 spills
// the 64-VGPR A-fragment array to scratch (640 MB of HBM traffic, 2.3x slower).
__global__ __launch_bounds__(512, 2) void k_main(const unsigned short* __restrict__ zb,
                                                 float* __restrict__ S) {
  __shared__ __align__(16) unsigned short Bs[2][BCOL * KDIM];  // 128 KiB
  const int t    = threadIdx.x;
  const int w    = t >> 6;
  const int l    = t & 63;
  const int q    = l >> 4;    // quad within wave
  const int c15  = l & 15;
  const int bt      = blockIdx.x >> 2;
  const int quarter = blockIdx.x & 3;
  const int mg   = w >> 2;    // which 64-row group
  const int ns   = w & 3;     // which 64-col strip
  const int rbase = bt * BROW + mg * 64;

  // Per-lane DMA source byte offsets (within one 64 KB tile) for 8 issues.
  // Physical granule p = (w*8+j)*64 + l ; row=p>>4, pg=p&15 ; source data
  // granule k8 = pg ^ (row&15).
  int srcoff[8];
#pragma unroll
  for (int j = 0; j < 8; ++j) {
    int p   = (w * 8 + j) * 64 + l;
    int row = p >> 4;
    int pg  = p & 15;
    int k8  = pg ^ (row & 15);
    srcoff[j] = (row * 16 + k8) * 16;   // bytes
  }

  const char* tile0 = (const char*)zb + (size_t)(quarter * NQUARTER) * KDIM * 2;

  // Kick off DMA for tile 0 into buffer 0.
#pragma unroll
  for (int j = 0; j < 8; ++j)
    __builtin_amdgcn_global_load_lds((gas_ptr)(tile0 + srcoff[j]),
                                     (las_ptr)(&Bs[0][(w * 8 + j) * 512]), 16, 0, 0);

  // A fragments: a-frag layout (16x16x32): lane holds A[m=lane&15][k=q*8+j]
  bf16x8 afr[4][4];
#pragma unroll
  for (int m = 0; m < 4; ++m) {
    const unsigned short* ap = zb + (size_t)(rbase + m * 16 + c15) * KDIM + q * 8;
#pragma unroll
    for (int s = 0; s < 4; ++s)
      afr[m][s] = *reinterpret_cast<const bf16x8*>(ap + s * 32);
  }

  float rowsum[4][4];
#pragma unroll
  for (int m = 0; m < 4; ++m)
#pragma unroll
    for (int r = 0; r < 4; ++r) rowsum[m][r] = 0.f;

  for (int it = 0; it < NITER; ++it) {
    const int buf = it & 1;
    const int C0  = quarter * NQUARTER + it * BCOL;
    // Drains this wave's DMA (vmcnt) then barriers: tile `it` is fully in LDS,
    // and every wave has finished reading buffer buf^1 (done last iteration).
    __syncthreads();

    // Issue DMA for tile it+1 into the other buffer; completes during compute.
    if (it + 1 < NITER) {
      const char* src = tile0 + (size_t)(it + 1) * BCOL * KDIM * 2;
#pragma unroll
      for (int j = 0; j < 8; ++j)
        __builtin_amdgcn_global_load_lds((gas_ptr)(src + srcoff[j]),
                                         (las_ptr)(&Bs[buf ^ 1][(w * 8 + j) * 512]), 16, 0, 0);
    }

    f32x4 acc[4][4];
#pragma unroll
    for (int m = 0; m < 4; ++m)
#pragma unroll
      for (int n = 0; n < 4; ++n) acc[m][n] = (f32x4){0.f, 0.f, 0.f, 0.f};

#pragma unroll
    for (int s = 0; s < 4; ++s) {
      bf16x8 bfr[4];
#pragma unroll
      for (int n = 0; n < 4; ++n) {
        int rloc = ns * 64 + n * 16 + c15;
        int pg   = (s * 4 + q) ^ (rloc & 15);
        bfr[n] = *reinterpret_cast<const bf16x8*>(&Bs[buf][rloc * KDIM + pg * 8]);
      }
#pragma unroll
      for (int m = 0; m < 4; ++m)
#pragma unroll
        for (int n = 0; n < 4; ++n)
          acc[m][n] = __builtin_amdgcn_mfma_f32_16x16x32_bf16(afr[m][s], bfr[n], acc[m][n], 0, 0, 0);
    }

    // epilogue: exp2 (inputs pre-scaled) and row-sum; mask diagonal when this
    // wave's 64x64 strip sits on it (wave-uniform condition)
    const bool diagTile = (C0 + ns * 64) == rbase;
    if (diagTile) {
#pragma unroll
      for (int m = 0; m < 4; ++m)
#pragma unroll
        for (int n = 0; n < 4; ++n)
#pragma unroll
          for (int r = 0; r < 4; ++r) {
            float e = EXP2F(acc[m][n][r]);
            if ((m == n) && (c15 == q * 4 + r)) e = 0.f;  // sim[i][i] masked
            rowsum[m][r] += e;
          }
    } else {
#pragma unroll
      for (int m = 0; m < 4; ++m)
#pragma unroll
        for (int n = 0; n < 4; ++n)
#pragma unroll
          for (int r = 0; r < 4; ++r) {
            rowsum[m][r] += EXP2F(acc[m][n][r]);
          }
    }
  }

  // reduce across 16 column-lanes (xor 1,2,4,8 stay within quads), then one
  // atomicAdd per row-partial (4 per S element across the col-quarters)
#pragma unroll
  for (int m = 0; m < 4; ++m)
#pragma unroll
    for (int r = 0; r < 4; ++r) {
      float v = rowsum[m][r];
      v += __shfl_xor(v, 1);
      v += __shfl_xor(v, 2);
      v += __shfl_xor(v, 4);
      v += __shfl_xor(v, 8);
      if (c15 == 0) atomicAdd(&S[rbase + m * 16 + q * 4 + r], v);
    }
}

// ---- K3: loss_i = log(S_i) - 2*z_i.z_pair(i); mean into out ----
__global__ void k_final(const float* __restrict__ z, const float* __restrict__ S,
                        float* __restrict__ out) {
  __shared__ float red[256];
  int t = threadIdx.x;
  int i = blockIdx.x * 256 + t;
  int j = i ^ NHALF;  // positive pair index
  const float4* zi = reinterpret_cast<const float4*>(z + (size_t)i * KDIM);
  const float4* zj = reinterpret_cast<const float4*>(z + (size_t)j * KDIM);
  float dot = 0.f;
#pragma unroll
  for (int k = 0; k < KDIM / 4; ++k) {
    float4 a = zi[k], b = zj[k];
    dot += a.x * b.x + a.y * b.y + a.z * b.z + a.w * b.w;
  }
  float loss = LOG2F(S[i]) * 0.69314718055994531f - 2.f * dot;
  red[t] = loss;
  __syncthreads();
  for (int o = 128; o > 0; o >>= 1) {
    if (t < o) red[t] += red[t + o];
    __syncthreads();
  }
  if (t == 0) atomicAdd(out, red[0] * (1.f / N2));
}

extern "C" void kernel_launch(void* const* d_in, const int* in_sizes, int n_in,
                              void* d_out, int out_size, void* d_ws, size_t ws_size,
                              hipStream_t stream) {
  const float* z = (const float*)d_in[0];
  float* out = (float*)d_out;
  unsigned short* zb = (unsigned short*)d_ws;                       // 4 MB bf16 copy of z
  float* S = (float*)((char*)d_ws + (size_t)N2 * KDIM * 2);         // 64 KB row sums

  k_convert<<<(N2 * KDIM / 4) / 256, 256, 0, stream>>>(z, zb, S, out);
  k_main<<<512, 512, 0, stream>>>(zb, S);
  k_final<<<N2 / 256, 256, 0, stream>>>(z, S, out);
}